// Round 11
// baseline (334.449 us; speedup 1.0000x reference)
//
#include <hip/hip_runtime.h>
#include <hip/hip_bf16.h>

// Problem constants (fixed by setup_inputs)
#define BS   4
#define NQ   6400
#define DIMS 256
#define NH   8
#define NP   4
#define GW   80
#define GH   80

typedef __hip_bfloat16 bf16;
typedef unsigned short ushort;
typedef __attribute__((ext_vector_type(8))) short short8;   // 8 bf16 (MFMA A/B frag)
typedef __attribute__((ext_vector_type(4))) float floatx4;  // MFMA C/D frag

union bfu { bf16 h; ushort s; };
__device__ __forceinline__ ushort f2bs(float x) { bfu u; u.h = __float2bfloat16(x); return u.s; }
__device__ __forceinline__ float bs2f(ushort s) { return __uint_as_float(((unsigned)s) << 16); }
__device__ __forceinline__ float ldin(const void* p, size_t i, int isf) {
    return isf ? ((const float*)p)[i] : bs2f(((const ushort*)p)[i]);
}
#define MFMA16(a, b, c) __builtin_amdgcn_mfma_f32_16x16x32_bf16((a), (b), (c), 0, 0, 0)

// ---------------------------------------------------------------------------
// wprep: weights -> bf16 B^T[n][k]; biases -> f32; publishes dtype flag.
// Runs first (tiny). Self-detects dtype from query's first 256 half-words.
// ---------------------------------------------------------------------------
__global__ __launch_bounds__(256) void wprep_k(
    const void* __restrict__ query,
    const void* __restrict__ Wv, const void* __restrict__ bv,
    const void* __restrict__ Woff, const void* __restrict__ boff,
    const void* __restrict__ Wattn, const void* __restrict__ battn,
    const void* __restrict__ Wo, const void* __restrict__ bo,
    int* __restrict__ flagp,
    ushort* __restrict__ WvT, ushort* __restrict__ WoaT, ushort* __restrict__ WoT,
    float* __restrict__ biasv, float* __restrict__ biasoa, float* __restrict__ biaso)
{
    __shared__ int sflag;
    if (threadIdx.x == 0) sflag = 0;
    __syncthreads();
    {
        const ushort v = ((const ushort*)query)[threadIdx.x];
        if (((v >> 7) & 0xFF) > 160) atomicOr(&sflag, 1);
    }
    __syncthreads();
    const int isf = sflag;
    if (blockIdx.x == 0 && threadIdx.x == 0) *flagp = isf;

    const int i = blockIdx.x * 256 + threadIdx.x;
    const int n1 = 256 * 256, n2 = n1 + 192 * 512, n3 = n2 + 256 * 256;
    const int n4 = n3 + 256, n5 = n4 + 192, n6 = n5 + 256;
    if (i < n1) {
        int n = i >> 8, k = i & 255;
        WvT[i] = f2bs(ldin(Wv, (size_t)k * 256 + n, isf));
    } else if (i < n2) {
        int j = i - n1, n = j >> 9, k = j & 511;
        float v = (n < 128) ? ldin(Woff, (size_t)k * 128 + n, isf)
                            : ldin(Wattn, (size_t)k * 64 + (n - 128), isf);
        WoaT[j] = f2bs(v);
    } else if (i < n3) {
        int j = i - n2, n = j >> 8, k = j & 255;
        WoT[j] = f2bs(ldin(Wo, (size_t)k * 256 + n, isf));
    } else if (i < n4) {
        biasv[i - n3] = ldin(bv, i - n3, isf);
    } else if (i < n5) {
        int j = i - n4;
        biasoa[j] = (j < 128) ? ldin(boff, j, isf) : ldin(battn, j - 128, isf);
    } else if (i < n6) {
        biaso[i - n5] = ldin(bo, i - n5, isf);
    }
}

// ---------------------------------------------------------------------------
// prepv: fused input-convert + value projection (GEMM1).
// Block = 64 consecutive v rows (one interleaved-value batch bq; 64 | 6400).
// Stage source rows (converted to bf16) into LDS (also writing qb/vbv when
// f32), then MFMA against L2-resident WvT, bounce, write v_ws coalesced.
// GEMM1's A read is fused with the conversion read: zero extra HBM traffic.
// ---------------------------------------------------------------------------
__global__ __launch_bounds__(256) void prepv_k(
    const void* __restrict__ query, const void* __restrict__ voxbev,
    const ushort* __restrict__ WvT, const float* __restrict__ biasv,
    ushort* __restrict__ qb, ushort* __restrict__ vbv,
    ushort* __restrict__ v_ws)
{
    __shared__ __align__(16) short av[64 * 264];   // 33.8 KB
    __shared__ int sflag;
    const int tid = threadIdx.x;
    if (tid == 0) sflag = 0;
    __syncthreads();
    {
        const ushort v = ((const ushort*)query)[tid];
        if (((v >> 7) & 0xFF) > 160) atomicOr(&sflag, 1);
    }
    __syncthreads();
    const int isf = sflag;

    const int bm = blockIdx.x * 64;               // v row base
    const int bq = bm / NQ;
    const int q0 = bm - bq * NQ;
    const void* src = (bq & 1) ? voxbev : query;
    ushort* cdst = (bq & 1) ? vbv : qb;
    const size_t srow0 = (size_t)((bq >> 1) * NQ + q0);

    const int row = tid >> 2, seg = tid & 3;      // 64 shorts (128 B) per (row,seg)
    if (isf) {
        const float4* s = (const float4*)src + (srow0 + row) * 64 + seg * 16;
        float4 f[16];
        #pragma unroll
        for (int i = 0; i < 16; ++i) f[i] = s[i];
        ushort o[64];
        #pragma unroll
        for (int i = 0; i < 16; ++i) {
            o[i*4+0] = f2bs(f[i].x); o[i*4+1] = f2bs(f[i].y);
            o[i*4+2] = f2bs(f[i].z); o[i*4+3] = f2bs(f[i].w);
        }
        uint4* g = (uint4*)(cdst + (srow0 + row) * DIMS + seg * 64);
        #pragma unroll
        for (int i = 0; i < 8; ++i) {
            const uint4 u = ((const uint4*)o)[i];
            *(uint4*)&av[row * 264 + seg * 64 + i * 8] = u;
            g[i] = u;
        }
    } else {
        const uint4* s = (const uint4*)((const ushort*)src + (srow0 + row) * DIMS + seg * 64);
        uint4 u[8];
        #pragma unroll
        for (int i = 0; i < 8; ++i) u[i] = s[i];
        #pragma unroll
        for (int i = 0; i < 8; ++i)
            *(uint4*)&av[row * 264 + seg * 64 + i * 8] = u[i];
    }
    __syncthreads();

    // MFMA: wave = 64 rows x 64 cols (4 m-frags x 4 n-frags x 8 k-steps)
    const int lane = tid & 63, wv = tid >> 6;
    const int fr = lane & 15, fq = (lane >> 4) * 8;
    floatx4 acc[4][4] = {};
    #pragma unroll
    for (int k0 = 0; k0 < 256; k0 += 32) {
        short8 bf[4], af[4];
        #pragma unroll
        for (int nf = 0; nf < 4; ++nf)
            bf[nf] = *(const short8*)&WvT[(size_t)(wv * 64 + nf * 16 + fr) * 256 + k0 + fq];
        #pragma unroll
        for (int mf = 0; mf < 4; ++mf)
            af[mf] = *(const short8*)&av[(mf * 16 + fr) * 264 + k0 + fq];
        #pragma unroll
        for (int mf = 0; mf < 4; ++mf)
            #pragma unroll
            for (int nf = 0; nf < 4; ++nf)
                acc[mf][nf] = MFMA16(af[mf], bf[nf], acc[mf][nf]);
    }
    __syncthreads();                              // av dead -> reuse as bounce

    // bounce (C/D layout: col=lane&15, row=(lane>>4)*4+reg — m89-verified)
    const int col = lane & 15, rq4 = (lane >> 4) * 4;
    #pragma unroll
    for (int mf = 0; mf < 4; ++mf)
        #pragma unroll
        for (int nf = 0; nf < 4; ++nf) {
            const int gc = wv * 64 + nf * 16 + col;
            #pragma unroll
            for (int r = 0; r < 4; ++r)
                av[(mf * 16 + rq4 + r) * 264 + gc] = (short)f2bs(acc[mf][nf][r] + biasv[gc]);
        }
    __syncthreads();
    // coalesced v_ws write
    uint4* d = (uint4*)(v_ws + (size_t)(bm + row) * DIMS + seg * 64);
    #pragma unroll
    for (int i = 0; i < 8; ++i)
        d[i] = *(const uint4*)&av[row * 264 + seg * 64 + i * 8];
}

// ---------------------------------------------------------------------------
// mega: per block = 16 queries of ONE batch (XCD-swizzled).
// Phase 0: MFMA qcat(16x512) @ WoaT -> offsets/logits in LDS (f32).
// Then per-thread (q,queue,h) softmax + pixel coords (registers).
// Phase 1: gathers: 4 points x 4 corners x 32 dims (batch-8 dwordx4, MLP 8);
//          queue-merge through LDS -> bf16 sampled rows (16x256).
// Phase 2: MFMA sampled @ WoT + biaso + residual(query) -> d_out.
// ---------------------------------------------------------------------------
__global__ __launch_bounds__(256) void mega_k(
    const void* __restrict__ query, const void* __restrict__ voxbev,
    const ushort* __restrict__ qb, const ushort* __restrict__ vbv,
    const ushort* __restrict__ v_ws,
    const ushort* __restrict__ WoaT, const float* __restrict__ biasoa,
    const ushort* __restrict__ WoT, const float* __restrict__ biaso,
    const void* __restrict__ refpts, const int* __restrict__ flagp,
    void* __restrict__ out)
{
    __shared__ __align__(16) short aq[16 * 520];      // 16.6 KB (alias: samp16 16x264)
    __shared__ __align__(16) float res[16 * 201];     // 12.9 KB
    __shared__ __align__(16) float qsum[16 * 8 * 33]; // 16.9 KB
    const int isf = *flagp;
    const int tid = threadIdx.x, lane = tid & 63, wv = tid >> 6;

    const int bid = blockIdx.x;
    const int slot = bid & 7, b = slot >> 1;
    const int q0 = (((bid >> 3) << 1) + (slot & 1)) * 16;   // [0,6400) step 16

    // ---- phase 0: stage qcat A (16 rows x 512 bf16)
    const ushort* qsrc = isf ? qb : (const ushort*)query;
    const ushort* vsrc = isf ? vbv : (const ushort*)voxbev;
    const ushort* lo = ((b & 1) ? vsrc : qsrc) + ((size_t)(b >> 1) * NQ + q0) * DIMS;
    const ushort* hi = qsrc + ((size_t)b * NQ + q0) * DIMS;
    {
        const int r = tid >> 4, seg = tid & 15;   // 32 shorts each
        const ushort* s = (seg < 8) ? (lo + (size_t)r * DIMS + seg * 32)
                                    : (hi + (size_t)r * DIMS + (seg - 8) * 32);
        #pragma unroll
        for (int i = 0; i < 4; ++i)
            *(uint4*)&aq[r * 520 + seg * 32 + i * 8] = *(const uint4*)(s + i * 8);
    }
    __syncthreads();
    // MFMA0: wave = 16 rows x 48 cols, K=512
    {
        const int fr = lane & 15, fq = (lane >> 4) * 8;
        floatx4 acc[3] = {};
        #pragma unroll
        for (int k0 = 0; k0 < 512; k0 += 32) {
            const short8 af = *(const short8*)&aq[fr * 520 + k0 + fq];
            #pragma unroll
            for (int nf = 0; nf < 3; ++nf) {
                const short8 bf = *(const short8*)&WoaT[(size_t)(wv * 48 + nf * 16 + fr) * 512 + k0 + fq];
                acc[nf] = MFMA16(af, bf, acc[nf]);
            }
        }
        const int col = lane & 15, rq4 = (lane >> 4) * 4;
        #pragma unroll
        for (int nf = 0; nf < 3; ++nf) {
            const int gc = wv * 48 + nf * 16 + col;
            #pragma unroll
            for (int r = 0; r < 4; ++r)
                res[(rq4 + r) * 201 + gc] = acc[nf][r] + biasoa[gc];
        }
    }
    __syncthreads();

    // ---- per-thread softmax + coords: thread = (q, queue, h)
    const int q = tid >> 4, queue = (tid >> 3) & 1, h = tid & 7;
    float px[4], py[4], pw[4];
    {
        const float* rr = &res[q * 201];
        const float* al = rr + 128 + h * 8 + queue * 4;
        const float l0 = al[0], l1 = al[1], l2 = al[2], l3 = al[3];
        const float mx = fmaxf(fmaxf(l0, l1), fmaxf(l2, l3));
        const float e0 = __expf(l0 - mx), e1 = __expf(l1 - mx);
        const float e2 = __expf(l2 - mx), e3 = __expf(l3 - mx);
        const float inv = 0.5f / (e0 + e1 + e2 + e3);   // fold queue-mean 0.5
        const int bq2 = b * 2 + queue;
        const float rx = ldin(refpts, ((size_t)bq2 * NQ + q0 + q) * 2 + 0, isf);
        const float ry = ldin(refpts, ((size_t)bq2 * NQ + q0 + q) * 2 + 1, isf);
        const float* od = rr + h * 16 + queue * 8;
        pw[0] = e0 * inv; pw[1] = e1 * inv; pw[2] = e2 * inv; pw[3] = e3 * inv;
        #pragma unroll
        for (int p = 0; p < NP; ++p) {
            px[p] = rx * (float)GW + od[p * 2 + 0] - 0.5f;
            py[p] = ry * (float)GH + od[p * 2 + 1] - 0.5f;
        }
    }

    // ---- phase 1: gather 32 dims of head h for (q0+q, queue)
    float a[32] = {};
    {
        const ushort* vb = v_ws + (size_t)(b * 2 + queue) * NQ * DIMS + h * 32;
        #pragma unroll
        for (int p = 0; p < NP; ++p) {
            const float x = px[p], y = py[p], w = pw[p];
            const float x0f = floorf(x), y0f = floorf(y);
            const float dx = x - x0f, dy = y - y0f;
            const int x0 = (int)x0f, y0 = (int)y0f;
            float cw[4] = { w * (1.0f - dx) * (1.0f - dy), w * dx * (1.0f - dy),
                            w * (1.0f - dx) * dy,          w * dx * dy };
            int pidx[4];
            #pragma unroll
            for (int c = 0; c < 4; ++c) {
                const int xs = x0 + (c & 1), ys = y0 + (c >> 1);
                const bool ok = (unsigned)xs < (unsigned)GW && (unsigned)ys < (unsigned)GH;
                pidx[c] = min(max(ys, 0), GH - 1) * GW + min(max(xs, 0), GW - 1);
                if (!ok) cw[c] = 0.0f;
            }
            #pragma unroll
            for (int cp = 0; cp < 2; ++cp) {      // 2 corners per batch: 8 loads in flight
                uint4 d[8];
                #pragma unroll
                for (int c = 0; c < 2; ++c)
                    #pragma unroll
                    for (int i = 0; i < 4; ++i)
                        d[c * 4 + i] = *(const uint4*)(vb + (size_t)pidx[cp * 2 + c] * DIMS + i * 8);
                #pragma unroll
                for (int c = 0; c < 2; ++c) {
                    const float cc = cw[cp * 2 + c];
                    #pragma unroll
                    for (int i = 0; i < 4; ++i) {
                        const uint4 u = d[c * 4 + i];
                        a[i*8+0] += cc * bs2f((ushort)u.x); a[i*8+1] += cc * bs2f((ushort)(u.x >> 16));
                        a[i*8+2] += cc * bs2f((ushort)u.y); a[i*8+3] += cc * bs2f((ushort)(u.y >> 16));
                        a[i*8+4] += cc * bs2f((ushort)u.z); a[i*8+5] += cc * bs2f((ushort)(u.z >> 16));
                        a[i*8+6] += cc * bs2f((ushort)u.w); a[i*8+7] += cc * bs2f((ushort)(u.w >> 16));
                    }
                }
            }
        }
    }
    // queue-merge: queue0 parks f32 in LDS; queue1 adds, converts, writes samp16
    ushort* samp16 = (ushort*)aq;                 // 16 x 264 (alias, aq dead)
    float* qs = &qsum[(q * 8 + h) * 33];
    if (queue == 0) {
        #pragma unroll
        for (int i = 0; i < 32; ++i) qs[i] = a[i];
    }
    __syncthreads();
    if (queue == 1) {
        ushort o[32];
        #pragma unroll
        for (int i = 0; i < 32; ++i) o[i] = f2bs(qs[i] + a[i]);
        #pragma unroll
        for (int i = 0; i < 4; ++i)
            *(uint4*)&samp16[q * 264 + h * 32 + i * 8] = ((const uint4*)o)[i];
    }
    __syncthreads();

    // ---- phase 2: out = samp16 @ WoT + biaso + residual(query)
    {
        const int fr = lane & 15, fq = (lane >> 4) * 8;
        floatx4 acc[4] = {};
        #pragma unroll
        for (int k0 = 0; k0 < 256; k0 += 32) {
            const short8 af = *(const short8*)&samp16[fr * 264 + k0 + fq];
            #pragma unroll
            for (int nf = 0; nf < 4; ++nf) {
                const short8 bf = *(const short8*)&WoT[(size_t)(wv * 64 + nf * 16 + fr) * 256 + k0 + fq];
                acc[nf] = MFMA16(af, bf, acc[nf]);
            }
        }
        const int col = lane & 15, rq4 = (lane >> 4) * 4;
        #pragma unroll
        for (int nf = 0; nf < 4; ++nf) {
            const int gc = wv * 64 + nf * 16 + col;
            #pragma unroll
            for (int r = 0; r < 4; ++r) {
                const int lrow = rq4 + r;         // 0..15, all valid
                const size_t g = ((size_t)b * NQ + q0 + lrow) * DIMS + gc;
                const float x = acc[nf][r] + biaso[gc] + ldin(query, g, isf);
                if (isf) ((float*)out)[g] = x;
                else     ((ushort*)out)[g] = f2bs(x);
            }
        }
    }
}

// ---------------------------------------------------------------------------
extern "C" void kernel_launch(void* const* d_in, const int* in_sizes, int n_in,
                              void* d_out, int out_size, void* d_ws, size_t ws_size,
                              hipStream_t stream)
{
    const void* query  = d_in[0];
    const void* voxbev = d_in[1];
    const void* refpts = d_in[2];
    // d_in[3] spatial_shapes=[[80,80]], d_in[4] level_start_index=[0]: hardcoded
    const void* Wv   = d_in[5];  const void* bv    = d_in[6];
    const void* Woff = d_in[7];  const void* boff  = d_in[8];
    const void* Wattn= d_in[9];  const void* battn = d_in[10];
    const void* Wo   = d_in[11]; const void* bo    = d_in[12];

    // workspace (~53.5 MB)
    char* p = (char*)d_ws;
    int* flag = (int*)p;             p += 256;
    ushort* WvT  = (ushort*)p;       p += 256 * 256 * 2;
    ushort* WoaT = (ushort*)p;       p += 192 * 512 * 2;
    ushort* WoT  = (ushort*)p;       p += 256 * 256 * 2;
    float* biasv  = (float*)p;       p += 1024;
    float* biasoa = (float*)p;       p += 1024;
    float* biaso  = (float*)p;       p += 1024;
    ushort* qb   = (ushort*)p;       p += (size_t)BS * NQ * DIMS * 2;       // 13.1 MB
    ushort* vbv  = (ushort*)p;       p += (size_t)BS * NQ * DIMS * 2;       // 13.1 MB
    ushort* v_ws = (ushort*)p;       p += (size_t)2 * BS * NQ * DIMS * 2;   // 26.2 MB

    // 1. weights + flag (tiny, runs first: provides WvT for prepv)
    wprep_k<<<899, 256, 0, stream>>>(query, Wv, bv, Woff, boff, Wattn, battn,
                                     Wo, bo, flag, WvT, WoaT, WoT,
                                     biasv, biasoa, biaso);

    // 2. fused convert + value projection: v_ws (and qb/vbv when f32)
    prepv_k<<<800, 256, 0, stream>>>(query, voxbev, WvT, biasv, qb, vbv, v_ws);

    // 3. fused offsets-GEMM + softmax + sampling + output-GEMM + residual
    mega_k<<<1600, 256, 0, stream>>>(query, voxbev, qb, vbv, v_ws,
                                     WoaT, biasoa, WoT, biaso,
                                     refpts, flag, d_out);
}